// Round 17
// baseline (162.808 us; speedup 1.0000x reference)
//
#include <hip/hip_runtime.h>

typedef __bf16 bf16x8 __attribute__((ext_vector_type(8)));
typedef float f32x4 __attribute__((ext_vector_type(4)));
typedef unsigned short u16x8 __attribute__((ext_vector_type(8)));
typedef short s16x4 __attribute__((ext_vector_type(4)));

__device__ __forceinline__ unsigned short f2b(float f) {
    union { float f; unsigned u; } v; v.f = f;
    unsigned r = (v.u + 0x7fffu + ((v.u >> 16) & 1u)) >> 16;
    return (unsigned short)r;
}

__device__ __forceinline__ float b2f(unsigned short b) {
    union { unsigned u; float f; } v; v.u = ((unsigned)b) << 16;
    return v.f;
}

__device__ __forceinline__ void load_lds16(const void* g, void* l) {
    __builtin_amdgcn_global_load_lds(
        (const __attribute__((address_space(1))) unsigned int*)g,
        (__attribute__((address_space(3))) unsigned int*)l,
        16, 0, 0);
}

// ---------------- fused f32 -> bf16 conversion (all 5 tensors, one launch) ----------------
__global__ void cvt5_kernel(const float* __restrict__ s0, const float* __restrict__ s1,
                            const float* __restrict__ s2, const float* __restrict__ s3,
                            const float* __restrict__ s4,
                            unsigned short* __restrict__ d0, unsigned short* __restrict__ d1,
                            unsigned short* __restrict__ d2, unsigned short* __restrict__ d3,
                            unsigned short* __restrict__ d4) {
    int i = blockIdx.x * 256 + threadIdx.x;     // f32x4 index, total 2162688
    const float* s; unsigned short* d; int off;
    if (i < 786432)       { s = s0; d = d0; off = 0; }
    else if (i < 1228800) { s = s1; d = d1; off = 786432; }
    else if (i < 1376256) { s = s2; d = d2; off = 1228800; }
    else if (i < 1769472) { s = s3; d = d3; off = 1376256; }
    else                  { s = s4; d = d4; off = 1769472; }
    i -= off;
    f32x4 v = ((const f32x4*)s)[i];
    s16x4 o;
    o.x = (short)f2b(v.x);
    o.y = (short)f2b(v.y);
    o.z = (short)f2b(v.z);
    o.w = (short)f2b(v.w);
    ((s16x4*)d)[i] = o;
}

// ---------------- exp(bias) -> bf16 precompute ----------------
// attn_bias: 4*1024*1024 f32 = 1048576 f32x4  (grid 4096 x 256)
__global__ void expb_kernel(const float* __restrict__ bias, unsigned short* __restrict__ eb, int n4) {
    int i = blockIdx.x * 256 + threadIdx.x;
    if (i < n4) {
        f32x4 v = ((const f32x4*)bias)[i];
        s16x4 o;
#pragma unroll
        for (int e = 0; e < 4; e++) o[e] = (short)f2b(__expf(v[e]));
        ((s16x4*)eb)[i] = o;
    }
}

// ---------------- high-occupancy bf16 GEMM (R9, unchanged — proven) ----------------
// 64x64 tile, BK=64, 4 waves (2x2, each 32x32), LDS 32KB double-buffered -> 5 blocks/CU.
template <int EPI>
__global__ __launch_bounds__(256, 5)
void gemm_ho(const unsigned short* __restrict__ A, const unsigned short* __restrict__ Bm,
             const float* __restrict__ bias, void* __restrict__ Cout,
             int M, int N, int K) {
    __shared__ unsigned short As[2][64 * 64];
    __shared__ unsigned short Bs[2][64 * 64];
    const int tid = threadIdx.x, lane = tid & 63, wid = tid >> 6;
    const int l15 = lane & 15, lq = lane >> 4;
    const int wr = wid >> 1, wc = wid & 1;

    const int nwg = gridDim.x * gridDim.y;
    int bid = blockIdx.y * gridDim.x + blockIdx.x;
    bid = (bid & 7) * (nwg >> 3) + (bid >> 3);
    const int bx = bid % gridDim.x, by = bid / gridDim.x;
    const int m0 = by * 64, n0 = bx * 64;

    const int srow = lane >> 3;
    const int scol = ((lane & 7) ^ srow) * 8;
    const int sw = (l15 & 7) << 4;

    f32x4 acc[2][2];
#pragma unroll
    for (int i = 0; i < 2; i++)
#pragma unroll
        for (int j = 0; j < 2; j++) acc[i][j] = 0.0f;

    auto stage = [&](int buf, int kt) {
        const int kb = kt * 64;
#pragma unroll
        for (int i = 0; i < 4; ++i) {
            const int c = wid * 4 + i;
            if (c < 8) {
                load_lds16(A + (size_t)(m0 + c * 8 + srow) * K + kb + scol,
                           (char*)As[buf] + c * 1024);
            } else {
                load_lds16(Bm + (size_t)(n0 + (c - 8) * 8 + srow) * K + kb + scol,
                           (char*)Bs[buf] + (c - 8) * 1024);
            }
        }
    };

    auto compute = [&](int buf) {
#pragma unroll
        for (int kc = 0; kc < 2; ++kc) {
            const int cb = kc * 64;
            bf16x8 af[2], bf[2];
#pragma unroll
            for (int mi = 0; mi < 2; mi++) {
                const int row = wr * 32 + mi * 16 + l15;
                af[mi] = *(const bf16x8*)((const char*)As[buf] + row * 128 + ((cb + lq * 16) ^ sw));
            }
#pragma unroll
            for (int ni = 0; ni < 2; ni++) {
                const int row = wc * 32 + ni * 16 + l15;
                bf[ni] = *(const bf16x8*)((const char*)Bs[buf] + row * 128 + ((cb + lq * 16) ^ sw));
            }
#pragma unroll
            for (int mi = 0; mi < 2; mi++)
#pragma unroll
                for (int ni = 0; ni < 2; ni++)
                    acc[mi][ni] = __builtin_amdgcn_mfma_f32_16x16x32_bf16(af[mi], bf[ni], acc[mi][ni], 0, 0, 0);
        }
    };

    const int nkt = K / 64;
    stage(0, 0);
    stage(1, 1);
    asm volatile("s_waitcnt vmcnt(4)" ::: "memory");
    __builtin_amdgcn_s_barrier();
    int cur = 0;
    for (int t = 0; t < nkt; ++t) {
        compute(cur);
        __builtin_amdgcn_s_barrier();
        if (t + 2 < nkt) {
            stage(cur, t + 2);
            asm volatile("s_waitcnt vmcnt(4)" ::: "memory");
        } else if (t + 1 < nkt) {
            asm volatile("s_waitcnt vmcnt(0)" ::: "memory");
        }
        if (t + 1 < nkt) __builtin_amdgcn_s_barrier();
        cur ^= 1;
    }

#pragma unroll
    for (int mi = 0; mi < 2; mi++) {
#pragma unroll
        for (int ni = 0; ni < 2; ni++) {
            const int col = n0 + wc * 32 + ni * 16 + l15;
            const float bv = bias[col];
#pragma unroll
            for (int r = 0; r < 4; r++) {
                const int row = m0 + wr * 32 + mi * 16 + lq * 4 + r;
                float v = acc[mi][ni][r] + bv;
                if constexpr (EPI == 2) {
                    v = 0.5f * v * (1.0f + erff(v * 0.7071067811865475f));
                }
                if constexpr (EPI == 1) {
                    ((float*)Cout)[(size_t)row * N + col] = v;
                } else {
                    ((unsigned short*)Cout)[(size_t)row * N + col] = f2b(v);
                }
            }
        }
    }
}

// ---------------- big-M bf16 GEMM: 128x64 tile, 3 blocks/CU ----------------
// Same counted-vmcnt double-buffer protocol as gemm_ho; 4 waves in 2(M)x2(N),
// wave tile 64x32 (MR=4, NR=2) -> 16 MFMA per K-step per wave (2x amortization),
// and half the B-panel re-reads. LDS 48 KB.
template <int EPI>
__global__ __launch_bounds__(256, 3)
void gemm_hb(const unsigned short* __restrict__ A, const unsigned short* __restrict__ Bm,
             const float* __restrict__ bias, void* __restrict__ Cout,
             int M, int N, int K) {
    __shared__ unsigned short As[2][128 * 64];
    __shared__ unsigned short Bs[2][64 * 64];
    const int tid = threadIdx.x, lane = tid & 63, wid = tid >> 6;
    const int l15 = lane & 15, lq = lane >> 4;
    const int wr = wid >> 1, wc = wid & 1;

    const int nwg = gridDim.x * gridDim.y;
    int bid = blockIdx.y * gridDim.x + blockIdx.x;
    bid = (bid & 7) * (nwg >> 3) + (bid >> 3);
    const int bx = bid % gridDim.x, by = bid / gridDim.x;
    const int m0 = by * 128, n0 = bx * 64;

    const int srow = lane >> 3;
    const int scol = ((lane & 7) ^ srow) * 8;
    const int sw = (l15 & 7) << 4;

    f32x4 acc[4][2];
#pragma unroll
    for (int i = 0; i < 4; i++)
#pragma unroll
        for (int j = 0; j < 2; j++) acc[i][j] = 0.0f;

    // 24 chunks/tile (A:16, B:8); 6 per wave
    auto stage = [&](int buf, int kt) {
        const int kb = kt * 64;
#pragma unroll
        for (int i = 0; i < 6; ++i) {
            const int c = wid * 6 + i;
            if (c < 16) {
                load_lds16(A + (size_t)(m0 + c * 8 + srow) * K + kb + scol,
                           (char*)As[buf] + c * 1024);
            } else {
                load_lds16(Bm + (size_t)(n0 + (c - 16) * 8 + srow) * K + kb + scol,
                           (char*)Bs[buf] + (c - 16) * 1024);
            }
        }
    };

    auto compute = [&](int buf) {
#pragma unroll
        for (int kc = 0; kc < 2; ++kc) {
            const int cb = kc * 64;
            bf16x8 af[4], bf[2];
#pragma unroll
            for (int mi = 0; mi < 4; mi++) {
                const int row = wr * 64 + mi * 16 + l15;
                af[mi] = *(const bf16x8*)((const char*)As[buf] + row * 128 + ((cb + lq * 16) ^ sw));
            }
#pragma unroll
            for (int ni = 0; ni < 2; ni++) {
                const int row = wc * 32 + ni * 16 + l15;
                bf[ni] = *(const bf16x8*)((const char*)Bs[buf] + row * 128 + ((cb + lq * 16) ^ sw));
            }
#pragma unroll
            for (int mi = 0; mi < 4; mi++)
#pragma unroll
                for (int ni = 0; ni < 2; ni++)
                    acc[mi][ni] = __builtin_amdgcn_mfma_f32_16x16x32_bf16(af[mi], bf[ni], acc[mi][ni], 0, 0, 0);
        }
    };

    const int nkt = K / 64;
    stage(0, 0);
    stage(1, 1);
    asm volatile("s_waitcnt vmcnt(6)" ::: "memory");
    __builtin_amdgcn_s_barrier();
    int cur = 0;
    for (int t = 0; t < nkt; ++t) {
        compute(cur);
        __builtin_amdgcn_s_barrier();
        if (t + 2 < nkt) {
            stage(cur, t + 2);
            asm volatile("s_waitcnt vmcnt(6)" ::: "memory");
        } else if (t + 1 < nkt) {
            asm volatile("s_waitcnt vmcnt(0)" ::: "memory");
        }
        if (t + 1 < nkt) __builtin_amdgcn_s_barrier();
        cur ^= 1;
    }

#pragma unroll
    for (int mi = 0; mi < 4; mi++) {
#pragma unroll
        for (int ni = 0; ni < 2; ni++) {
            const int col = n0 + wc * 32 + ni * 16 + l15;
            const float bv = bias[col];
#pragma unroll
            for (int r = 0; r < 4; r++) {
                const int row = m0 + wr * 64 + mi * 16 + lq * 4 + r;
                float v = acc[mi][ni][r] + bv;
                if constexpr (EPI == 2) {
                    v = 0.5f * v * (1.0f + erff(v * 0.7071067811865475f));
                }
                if constexpr (EPI == 1) {
                    ((float*)Cout)[(size_t)row * N + col] = v;
                } else {
                    ((unsigned short*)Cout)[(size_t)row * N + col] = f2b(v);
                }
            }
        }
    }
}

// ---------------- flash attention (R16, unchanged — double-buffered K/V, 1 barrier/tile) --
__global__ __launch_bounds__(256, 2)
void attn_kernel(const unsigned short* __restrict__ qkv,
                 const unsigned short* __restrict__ eb,
                 unsigned short* __restrict__ out) {
    const int L = 1024, TD = 2304, HD = 96;
    const int qt = blockIdx.x, h = blockIdx.y, b = blockIdx.z;
    const int tid = threadIdx.x, lane = tid & 63, wid = tid >> 6;
    const int l15 = lane & 15, lq = lane >> 4;
    const int q0 = qt * 64;
    const float scale = 0.10206207261596576f; // 1/sqrt(96)

    __shared__ char smem[63488];
    auto KsP = [&](int p) { return (unsigned short (*)[104])(smem + p * 13312); };
    auto VtP = [&](int p) { return (unsigned short (*)[72])(smem + 26624 + p * 13824); };
    unsigned short (*Ps)[16][72] = (unsigned short (*)[16][72])(smem + 54272);
    float (*Ot)[16][100]         = (float (*)[16][100])smem;

    bf16x8 qf[3];
    const int qrow = q0 + wid * 16 + l15;
#pragma unroll
    for (int kc = 0; kc < 3; kc++)
        qf[kc] = *(const bf16x8*)(qkv + (size_t)(b * L + qrow) * TD + h * HD + kc * 32 + lq * 8);

    int krow[3], kcc[3];
#pragma unroll
    for (int i = 0; i < 3; i++) { int c = i * 256 + tid; krow[i] = c / 12; kcc[i] = c % 12; }

    f32x4 kreg[3]; u16x8 vreg[3];
    unsigned short ereg[4][4];
    const unsigned short* ebbase = eb + (size_t)(b * L + q0 + wid * 16 + lq * 4) * L;

    auto issueKV = [&](int kv0) {
#pragma unroll
        for (int i = 0; i < 3; i++)
            kreg[i] = *(const f32x4*)(qkv + (size_t)(b * L + kv0 + krow[i]) * TD + 768 + h * HD + kcc[i] * 8);
#pragma unroll
        for (int i = 0; i < 3; i++)
            vreg[i] = *(const u16x8*)(qkv + (size_t)(b * L + kv0 + lane) * TD + 1536 + h * HD + (i * 4 + wid) * 8);
    };
    auto issueEB = [&](int kv0) {
#pragma unroll
        for (int r = 0; r < 4; r++)
#pragma unroll
            for (int nf = 0; nf < 4; nf++)
                ereg[r][nf] = ebbase[(size_t)r * L + kv0 + nf * 16 + l15];
    };
    auto commitKV = [&](int p) {
        unsigned short (*Ks)[104] = KsP(p);
        unsigned short (*Vt)[72] = VtP(p);
#pragma unroll
        for (int i = 0; i < 3; i++) *(f32x4*)&Ks[krow[i]][kcc[i] * 8] = kreg[i];
#pragma unroll
        for (int i = 0; i < 3; i++) {
            const int dblk = i * 4 + wid;
#pragma unroll
            for (int j = 0; j < 8; j++) Vt[dblk * 8 + j][lane] = vreg[i][j];
        }
    };

    f32x4 o[6];
#pragma unroll
    for (int df = 0; df < 6; df++) o[df] = 0.0f;
    float lsum[4] = {0.f, 0.f, 0.f, 0.f};

    issueKV(0);
    issueEB(0);
    for (int t = 0; t < 16; ++t) {
        const int p = t & 1;
        asm volatile("s_waitcnt vmcnt(0)" ::: "memory");
        commitKV(p);
        asm volatile("s_waitcnt lgkmcnt(0)" ::: "memory");
        __builtin_amdgcn_s_barrier();

        unsigned short (*Ks)[104] = KsP(p);
        unsigned short (*Vt)[72] = VtP(p);
        f32x4 s[4];
#pragma unroll
        for (int nf = 0; nf < 4; nf++) s[nf] = 0.0f;
#pragma unroll
        for (int kc = 0; kc < 3; kc++) {
#pragma unroll
            for (int nf = 0; nf < 4; nf++) {
                bf16x8 kf = *(const bf16x8*)&Ks[nf * 16 + l15][kc * 32 + lq * 8];
                s[nf] = __builtin_amdgcn_mfma_f32_16x16x32_bf16(qf[kc], kf, s[nf], 0, 0, 0);
            }
        }
        if (t + 1 < 16) issueKV((t + 1) * 64);

#pragma unroll
        for (int nf = 0; nf < 4; nf++) {
#pragma unroll
            for (int r = 0; r < 4; r++) {
                float p2 = __expf(s[nf][r] * scale) * b2f(ereg[r][nf]);
                s[nf][r] = p2;
                lsum[r] += p2;
            }
        }
        if (t + 1 < 16) issueEB((t + 1) * 64);

#pragma unroll
        for (int nf = 0; nf < 4; nf++)
#pragma unroll
            for (int r = 0; r < 4; r++)
                Ps[wid][lq * 4 + r][nf * 16 + l15] = f2b(s[nf][r]);
        asm volatile("s_waitcnt lgkmcnt(0)" ::: "memory");
#pragma unroll
        for (int kc = 0; kc < 2; kc++) {
            bf16x8 pf = *(const bf16x8*)&Ps[wid][l15][kc * 32 + lq * 8];
#pragma unroll
            for (int df = 0; df < 6; df++) {
                bf16x8 vf = *(const bf16x8*)&Vt[df * 16 + l15][kc * 32 + lq * 8];
                o[df] = __builtin_amdgcn_mfma_f32_16x16x32_bf16(pf, vf, o[df], 0, 0, 0);
            }
        }
    }
    __builtin_amdgcn_s_barrier();

#pragma unroll
    for (int r = 0; r < 4; r++) {
#pragma unroll
        for (int d = 1; d < 16; d <<= 1) lsum[r] += __shfl_xor(lsum[r], d, 64);
    }

#pragma unroll
    for (int r = 0; r < 4; r++) {
        float inv = 1.0f / lsum[r];
        const int rl = lq * 4 + r;
#pragma unroll
        for (int df = 0; df < 6; df++) {
            const int cl = df * 16 + l15;
            Ot[wid][rl][cl ^ (lq << 3)] = o[df][r] * inv;
        }
    }
    asm volatile("s_waitcnt lgkmcnt(0)" ::: "memory");
    {
        const int r = lane >> 2, c8 = lane & 3;
        const int rowg = q0 + wid * 16 + r;
#pragma unroll
        for (int it = 0; it < 3; it++) {
            const int oc = c8 + 4 * it;
            const int po = oc ^ ((r >> 2) & 3);
            f32x4 a = *(const f32x4*)&Ot[wid][r][po * 8];
            f32x4 bb = *(const f32x4*)&Ot[wid][r][po * 8 + 4];
            u16x8 p;
#pragma unroll
            for (int e = 0; e < 4; e++) { p[e] = f2b(a[e]); p[e + 4] = f2b(bb[e]); }
            *(u16x8*)&out[((size_t)b * L + rowg) * 768 + h * 96 + oc * 8] = p;
        }
    }
}

// ---------------- residual + layernorm (vectorized f32x4) ----------------
template <int WRITE_B>
__global__ __launch_bounds__(256, 4)
void ln_kernel(const float* __restrict__ x, const float* __restrict__ res,
               const float* __restrict__ g, const float* __restrict__ bvec,
               float* __restrict__ outf, unsigned short* __restrict__ outb) {
    const int Dm = 768;
    int row = blockIdx.x;
    int tid = threadIdx.x;
    f32x4 v = {0.f, 0.f, 0.f, 0.f};
    float sum = 0.f, sq = 0.f;
    if (tid < 192) {
        f32x4 xv = ((const f32x4*)(x + (size_t)row * Dm))[tid];
        f32x4 rv = ((const f32x4*)(res + (size_t)row * Dm))[tid];
        v = xv + rv;
        sum = v.x + v.y + v.z + v.w;
        sq = v.x * v.x + v.y * v.y + v.z * v.z + v.w * v.w;
    }
#pragma unroll
    for (int d = 1; d < 64; d <<= 1) {
        sum += __shfl_xor(sum, d, 64);
        sq += __shfl_xor(sq, d, 64);
    }
    __shared__ float ps[8];
    int lane = tid & 63, wid = tid >> 6;
    if (lane == 0) { ps[wid] = sum; ps[wid + 4] = sq; }
    __syncthreads();
    sum = ps[0] + ps[1] + ps[2] + ps[3];
    sq = ps[4] + ps[5] + ps[6] + ps[7];
    float mu = sum * (1.0f / 768.0f);
    float var = sq * (1.0f / 768.0f) - mu * mu;
    float rsg = rsqrtf(var + 1e-5f);
    if (tid < 192) {
        f32x4 gv = ((const f32x4*)g)[tid];
        f32x4 bv = ((const f32x4*)bvec)[tid];
        f32x4 ov;
#pragma unroll
        for (int e = 0; e < 4; e++) ov[e] = (v[e] - mu) * rsg * gv[e] + bv[e];
        ((f32x4*)(outf + (size_t)row * Dm))[tid] = ov;
        if constexpr (WRITE_B) {
            s16x4 pb;
#pragma unroll
            for (int e = 0; e < 4; e++) pb[e] = (short)f2b(ov[e]);
            ((s16x4*)(outb + (size_t)row * Dm))[tid] = pb;
        }
    }
}

// ---------------- launch ----------------
extern "C" void kernel_launch(void* const* d_in, const int* in_sizes, int n_in,
                              void* d_out, int out_size, void* d_ws, size_t ws_size,
                              hipStream_t stream) {
    (void)in_sizes; (void)n_in; (void)out_size; (void)ws_size;
    const float* x         = (const float*)d_in[0];
    const float* attn_bias = (const float*)d_in[1];
    const float* in_proj_w = (const float*)d_in[2];
    const float* in_proj_b = (const float*)d_in[3];
    const float* out_w     = (const float*)d_in[4];
    const float* out_b     = (const float*)d_in[5];
    const float* ff1_w     = (const float*)d_in[6];
    const float* ff1_b     = (const float*)d_in[7];
    const float* ff2_w     = (const float*)d_in[8];
    const float* ff2_b     = (const float*)d_in[9];
    const float* ln1_g     = (const float*)d_in[10];
    const float* ln1_b     = (const float*)d_in[11];
    const float* ln2_g     = (const float*)d_in[12];
    const float* ln2_b     = (const float*)d_in[13];

    const int NTOK = 4096;        // B*L
    char* ws = (char*)d_ws;
    size_t off = 0;
    auto alloc = [&](size_t bytes) { void* p = ws + off; off += (bytes + 255) & ~(size_t)255; return p; };
    unsigned short* xb    = (unsigned short*)alloc((size_t)NTOK * 768 * 2);
    unsigned short* wqkv  = (unsigned short*)alloc((size_t)2304 * 768 * 2);
    unsigned short* wout  = (unsigned short*)alloc((size_t)768 * 768 * 2);
    unsigned short* wff1  = (unsigned short*)alloc((size_t)2048 * 768 * 2);
    unsigned short* wff2  = (unsigned short*)alloc((size_t)768 * 2048 * 2);
    unsigned short* qkvb  = (unsigned short*)alloc((size_t)NTOK * 2304 * 2);
    unsigned short* attnb = (unsigned short*)alloc((size_t)NTOK * 768 * 2);
    float*          aproj = (float*)alloc((size_t)NTOK * 768 * 4);
    float*          x1f   = (float*)alloc((size_t)NTOK * 768 * 4);
    unsigned short* x1b   = (unsigned short*)alloc((size_t)NTOK * 768 * 2);
    // aliases (lifetimes are disjoint):
    unsigned short* h1b  = qkvb;     // [4096,2048] bf16 fits in qkv region
    float*          ff2o = aproj;    // [4096,768] f32, aproj dead after LN1
    unsigned short* ebuf = (unsigned short*)aproj;  // exp(bias) bf16, 8.4MB <= 12.6MB;
                                                    // live [expb, attn] — aproj live [outproj, LN1]

    // fused f32 -> bf16 conversions + exp(bias) precompute (1048576 f32x4)
    cvt5_kernel<<<dim3(8448), 256, 0, stream>>>(x, in_proj_w, out_w, ff1_w, ff2_w,
                                                xb, wqkv, wout, wff1, wff2);
    expb_kernel<<<dim3(4096), 256, 0, stream>>>(attn_bias, ebuf, 1048576);

    // qkv = x @ in_proj_w^T + b        [4096, 2304] bf16   grid 36x32 = 1152 (3+/CU)
    gemm_hb<0><<<dim3(2304 / 64, NTOK / 128), 256, 0, stream>>>(xb, wqkv, in_proj_b, qkvb, NTOK, 2304, 768);
    // attention                         grid (16, 8, 4) = 512 blocks
    attn_kernel<<<dim3(16, 8, 4), 256, 0, stream>>>(qkvb, ebuf, attnb);
    // attn @ out_w^T + b               [4096, 768] f32     grid 12x64 = 768 (5/CU)
    gemm_ho<1><<<dim3(768 / 64, NTOK / 64), 256, 0, stream>>>(attnb, wout, out_b, aproj, NTOK, 768, 768);
    // x1 = LN1(x + aproj)              f32 + bf16
    ln_kernel<1><<<dim3(NTOK), 256, 0, stream>>>(x, aproj, ln1_g, ln1_b, x1f, x1b);
    // h = gelu(x1 @ ff1^T + b)         [4096, 2048] bf16   grid 32x32 = 1024 (3+/CU)
    gemm_hb<2><<<dim3(2048 / 64, NTOK / 128), 256, 0, stream>>>(x1b, wff1, ff1_b, h1b, NTOK, 2048, 768);
    // ff2 = h @ ff2^T + b              [4096, 768] f32     grid 12x64 = 768 (5/CU)
    gemm_ho<1><<<dim3(768 / 64, NTOK / 64), 256, 0, stream>>>(h1b, wff2, ff2_b, ff2o, NTOK, 768, 2048);
    // out = LN2(x1 + ff2)              f32 -> d_out
    ln_kernel<0><<<dim3(NTOK), 256, 0, stream>>>(x1f, ff2o, ln2_g, ln2_b, (float*)d_out, nullptr);
}

// Round 18
// 160.440 us; speedup vs baseline: 1.0148x; 1.0148x over previous
//
#include <hip/hip_runtime.h>

typedef __bf16 bf16x8 __attribute__((ext_vector_type(8)));
typedef float f32x4 __attribute__((ext_vector_type(4)));
typedef unsigned short u16x8 __attribute__((ext_vector_type(8)));
typedef short s16x4 __attribute__((ext_vector_type(4)));

__device__ __forceinline__ unsigned short f2b(float f) {
    union { float f; unsigned u; } v; v.f = f;
    unsigned r = (v.u + 0x7fffu + ((v.u >> 16) & 1u)) >> 16;
    return (unsigned short)r;
}

__device__ __forceinline__ float b2f(unsigned short b) {
    union { unsigned u; float f; } v; v.u = ((unsigned)b) << 16;
    return v.f;
}

__device__ __forceinline__ void load_lds16(const void* g, void* l) {
    __builtin_amdgcn_global_load_lds(
        (const __attribute__((address_space(1))) unsigned int*)g,
        (__attribute__((address_space(3))) unsigned int*)l,
        16, 0, 0);
}

// ------- fused f32 -> bf16 conversion (5 tensors) + exp(bias) -> bf16, one launch -------
// segments (f32x4 index): x 786432 | in_proj_w 442368 | out_w 147456 | ff1_w 393216 |
// ff2_w 393216 (cum 2162688) | exp(attn_bias) 1048576 (cum 3211264). grid 12544 x 256.
__global__ void cvt6_kernel(const float* __restrict__ s0, const float* __restrict__ s1,
                            const float* __restrict__ s2, const float* __restrict__ s3,
                            const float* __restrict__ s4, const float* __restrict__ s5,
                            unsigned short* __restrict__ d0, unsigned short* __restrict__ d1,
                            unsigned short* __restrict__ d2, unsigned short* __restrict__ d3,
                            unsigned short* __restrict__ d4, unsigned short* __restrict__ d5) {
    int i = blockIdx.x * 256 + threadIdx.x;
    const float* s; unsigned short* d; int off; bool ex = false;
    if (i < 786432)       { s = s0; d = d0; off = 0; }
    else if (i < 1228800) { s = s1; d = d1; off = 786432; }
    else if (i < 1376256) { s = s2; d = d2; off = 1228800; }
    else if (i < 1769472) { s = s3; d = d3; off = 1376256; }
    else if (i < 2162688) { s = s4; d = d4; off = 1769472; }
    else                  { s = s5; d = d5; off = 2162688; ex = true; }
    i -= off;
    f32x4 v = ((const f32x4*)s)[i];
    s16x4 o;
#pragma unroll
    for (int e = 0; e < 4; e++) o[e] = (short)f2b(ex ? __expf(v[e]) : v[e]);
    ((s16x4*)d)[i] = o;
}

// ---------------- high-occupancy bf16 GEMM (R9/R16, unchanged — proven best) ------------
// 64x64 tile, BK=64, 4 waves (2x2, each 32x32), LDS 32KB double-buffered -> 5 blocks/CU.
template <int EPI>
__global__ __launch_bounds__(256, 5)
void gemm_ho(const unsigned short* __restrict__ A, const unsigned short* __restrict__ Bm,
             const float* __restrict__ bias, void* __restrict__ Cout,
             int M, int N, int K) {
    __shared__ unsigned short As[2][64 * 64];
    __shared__ unsigned short Bs[2][64 * 64];
    const int tid = threadIdx.x, lane = tid & 63, wid = tid >> 6;
    const int l15 = lane & 15, lq = lane >> 4;
    const int wr = wid >> 1, wc = wid & 1;

    const int nwg = gridDim.x * gridDim.y;
    int bid = blockIdx.y * gridDim.x + blockIdx.x;
    bid = (bid & 7) * (nwg >> 3) + (bid >> 3);
    const int bx = bid % gridDim.x, by = bid / gridDim.x;
    const int m0 = by * 64, n0 = bx * 64;

    const int srow = lane >> 3;
    const int scol = ((lane & 7) ^ srow) * 8;
    const int sw = (l15 & 7) << 4;

    f32x4 acc[2][2];
#pragma unroll
    for (int i = 0; i < 2; i++)
#pragma unroll
        for (int j = 0; j < 2; j++) acc[i][j] = 0.0f;

    auto stage = [&](int buf, int kt) {
        const int kb = kt * 64;
#pragma unroll
        for (int i = 0; i < 4; ++i) {
            const int c = wid * 4 + i;
            if (c < 8) {
                load_lds16(A + (size_t)(m0 + c * 8 + srow) * K + kb + scol,
                           (char*)As[buf] + c * 1024);
            } else {
                load_lds16(Bm + (size_t)(n0 + (c - 8) * 8 + srow) * K + kb + scol,
                           (char*)Bs[buf] + (c - 8) * 1024);
            }
        }
    };

    auto compute = [&](int buf) {
#pragma unroll
        for (int kc = 0; kc < 2; ++kc) {
            const int cb = kc * 64;
            bf16x8 af[2], bf[2];
#pragma unroll
            for (int mi = 0; mi < 2; mi++) {
                const int row = wr * 32 + mi * 16 + l15;
                af[mi] = *(const bf16x8*)((const char*)As[buf] + row * 128 + ((cb + lq * 16) ^ sw));
            }
#pragma unroll
            for (int ni = 0; ni < 2; ni++) {
                const int row = wc * 32 + ni * 16 + l15;
                bf[ni] = *(const bf16x8*)((const char*)Bs[buf] + row * 128 + ((cb + lq * 16) ^ sw));
            }
#pragma unroll
            for (int mi = 0; mi < 2; mi++)
#pragma unroll
                for (int ni = 0; ni < 2; ni++)
                    acc[mi][ni] = __builtin_amdgcn_mfma_f32_16x16x32_bf16(af[mi], bf[ni], acc[mi][ni], 0, 0, 0);
        }
    };

    const int nkt = K / 64;
    stage(0, 0);
    stage(1, 1);
    asm volatile("s_waitcnt vmcnt(4)" ::: "memory");
    __builtin_amdgcn_s_barrier();
    int cur = 0;
    for (int t = 0; t < nkt; ++t) {
        compute(cur);
        __builtin_amdgcn_s_barrier();
        if (t + 2 < nkt) {
            stage(cur, t + 2);
            asm volatile("s_waitcnt vmcnt(4)" ::: "memory");
        } else if (t + 1 < nkt) {
            asm volatile("s_waitcnt vmcnt(0)" ::: "memory");
        }
        if (t + 1 < nkt) __builtin_amdgcn_s_barrier();
        cur ^= 1;
    }

#pragma unroll
    for (int mi = 0; mi < 2; mi++) {
#pragma unroll
        for (int ni = 0; ni < 2; ni++) {
            const int col = n0 + wc * 32 + ni * 16 + l15;
            const float bv = bias[col];
#pragma unroll
            for (int r = 0; r < 4; r++) {
                const int row = m0 + wr * 32 + mi * 16 + lq * 4 + r;
                float v = acc[mi][ni][r] + bv;
                if constexpr (EPI == 2) {
                    v = 0.5f * v * (1.0f + erff(v * 0.7071067811865475f));
                }
                if constexpr (EPI == 1) {
                    ((float*)Cout)[(size_t)row * N + col] = v;
                } else {
                    ((unsigned short*)Cout)[(size_t)row * N + col] = f2b(v);
                }
            }
        }
    }
}

// ---------------- flash attention (R16 structure) + XCD-bijective grid swizzle ----------
// Grid: 512 1-D blocks. swz=(bid&7)*64+(bid>>3) -> each XCD owns 64 contiguous tiles
// = 4 full (b,h) groups (tile = qt + 16*h + 128*b) -> K/V fetched once per XCD, eb rows
// shared across same-b tiles co-located. Double-buffered K/V, 1 barrier/tile, no-max
// softmax, T14 async reg staging, direct per-lane eb loads.
__global__ __launch_bounds__(256, 2)
void attn_kernel(const unsigned short* __restrict__ qkv,
                 const unsigned short* __restrict__ eb,
                 unsigned short* __restrict__ out) {
    const int L = 1024, TD = 2304, HD = 96;
    int bid = blockIdx.x;
    bid = (bid & 7) * 64 + (bid >> 3);            // XCD-bijective (nwg = 512)
    const int qt = bid & 15, h = (bid >> 4) & 7, b = bid >> 7;
    const int tid = threadIdx.x, lane = tid & 63, wid = tid >> 6;
    const int l15 = lane & 15, lq = lane >> 4;
    const int q0 = qt * 64;
    const float scale = 0.10206207261596576f; // 1/sqrt(96)

    __shared__ char smem[63488];
    auto KsP = [&](int p) { return (unsigned short (*)[104])(smem + p * 13312); };
    auto VtP = [&](int p) { return (unsigned short (*)[72])(smem + 26624 + p * 13824); };
    unsigned short (*Ps)[16][72] = (unsigned short (*)[16][72])(smem + 54272);
    float (*Ot)[16][100]         = (float (*)[16][100])smem;

    bf16x8 qf[3];
    const int qrow = q0 + wid * 16 + l15;
#pragma unroll
    for (int kc = 0; kc < 3; kc++)
        qf[kc] = *(const bf16x8*)(qkv + (size_t)(b * L + qrow) * TD + h * HD + kc * 32 + lq * 8);

    int krow[3], kcc[3];
#pragma unroll
    for (int i = 0; i < 3; i++) { int c = i * 256 + tid; krow[i] = c / 12; kcc[i] = c % 12; }

    f32x4 kreg[3]; u16x8 vreg[3];
    unsigned short ereg[4][4];
    const unsigned short* ebbase = eb + (size_t)(b * L + q0 + wid * 16 + lq * 4) * L;

    auto issueKV = [&](int kv0) {
#pragma unroll
        for (int i = 0; i < 3; i++)
            kreg[i] = *(const f32x4*)(qkv + (size_t)(b * L + kv0 + krow[i]) * TD + 768 + h * HD + kcc[i] * 8);
#pragma unroll
        for (int i = 0; i < 3; i++)
            vreg[i] = *(const u16x8*)(qkv + (size_t)(b * L + kv0 + lane) * TD + 1536 + h * HD + (i * 4 + wid) * 8);
    };
    auto issueEB = [&](int kv0) {
#pragma unroll
        for (int r = 0; r < 4; r++)
#pragma unroll
            for (int nf = 0; nf < 4; nf++)
                ereg[r][nf] = ebbase[(size_t)r * L + kv0 + nf * 16 + l15];
    };
    auto commitKV = [&](int p) {
        unsigned short (*Ks)[104] = KsP(p);
        unsigned short (*Vt)[72] = VtP(p);
#pragma unroll
        for (int i = 0; i < 3; i++) *(f32x4*)&Ks[krow[i]][kcc[i] * 8] = kreg[i];
#pragma unroll
        for (int i = 0; i < 3; i++) {
            const int dblk = i * 4 + wid;
#pragma unroll
            for (int j = 0; j < 8; j++) Vt[dblk * 8 + j][lane] = vreg[i][j];
        }
    };

    f32x4 o[6];
#pragma unroll
    for (int df = 0; df < 6; df++) o[df] = 0.0f;
    float lsum[4] = {0.f, 0.f, 0.f, 0.f};

    issueKV(0);
    issueEB(0);
    for (int t = 0; t < 16; ++t) {
        const int p = t & 1;
        asm volatile("s_waitcnt vmcnt(0)" ::: "memory");
        commitKV(p);
        asm volatile("s_waitcnt lgkmcnt(0)" ::: "memory");
        __builtin_amdgcn_s_barrier();

        unsigned short (*Ks)[104] = KsP(p);
        unsigned short (*Vt)[72] = VtP(p);
        f32x4 s[4];
#pragma unroll
        for (int nf = 0; nf < 4; nf++) s[nf] = 0.0f;
#pragma unroll
        for (int kc = 0; kc < 3; kc++) {
#pragma unroll
            for (int nf = 0; nf < 4; nf++) {
                bf16x8 kf = *(const bf16x8*)&Ks[nf * 16 + l15][kc * 32 + lq * 8];
                s[nf] = __builtin_amdgcn_mfma_f32_16x16x32_bf16(qf[kc], kf, s[nf], 0, 0, 0);
            }
        }
        if (t + 1 < 16) issueKV((t + 1) * 64);

#pragma unroll
        for (int nf = 0; nf < 4; nf++) {
#pragma unroll
            for (int r = 0; r < 4; r++) {
                float p2 = __expf(s[nf][r] * scale) * b2f(ereg[r][nf]);
                s[nf][r] = p2;
                lsum[r] += p2;
            }
        }
        if (t + 1 < 16) issueEB((t + 1) * 64);

#pragma unroll
        for (int nf = 0; nf < 4; nf++)
#pragma unroll
            for (int r = 0; r < 4; r++)
                Ps[wid][lq * 4 + r][nf * 16 + l15] = f2b(s[nf][r]);
        asm volatile("s_waitcnt lgkmcnt(0)" ::: "memory");
#pragma unroll
        for (int kc = 0; kc < 2; kc++) {
            bf16x8 pf = *(const bf16x8*)&Ps[wid][l15][kc * 32 + lq * 8];
#pragma unroll
            for (int df = 0; df < 6; df++) {
                bf16x8 vf = *(const bf16x8*)&Vt[df * 16 + l15][kc * 32 + lq * 8];
                o[df] = __builtin_amdgcn_mfma_f32_16x16x32_bf16(pf, vf, o[df], 0, 0, 0);
            }
        }
    }
    __builtin_amdgcn_s_barrier();

#pragma unroll
    for (int r = 0; r < 4; r++) {
#pragma unroll
        for (int d = 1; d < 16; d <<= 1) lsum[r] += __shfl_xor(lsum[r], d, 64);
    }

#pragma unroll
    for (int r = 0; r < 4; r++) {
        float inv = 1.0f / lsum[r];
        const int rl = lq * 4 + r;
#pragma unroll
        for (int df = 0; df < 6; df++) {
            const int cl = df * 16 + l15;
            Ot[wid][rl][cl ^ (lq << 3)] = o[df][r] * inv;
        }
    }
    asm volatile("s_waitcnt lgkmcnt(0)" ::: "memory");
    {
        const int r = lane >> 2, c8 = lane & 3;
        const int rowg = q0 + wid * 16 + r;
#pragma unroll
        for (int it = 0; it < 3; it++) {
            const int oc = c8 + 4 * it;
            const int po = oc ^ ((r >> 2) & 3);
            f32x4 a = *(const f32x4*)&Ot[wid][r][po * 8];
            f32x4 bb = *(const f32x4*)&Ot[wid][r][po * 8 + 4];
            u16x8 p;
#pragma unroll
            for (int e = 0; e < 4; e++) { p[e] = f2b(a[e]); p[e + 4] = f2b(bb[e]); }
            *(u16x8*)&out[((size_t)b * L + rowg) * 768 + h * 96 + oc * 8] = p;
        }
    }
}

// ---------------- residual + layernorm (vectorized f32x4) ----------------
template <int WRITE_B>
__global__ __launch_bounds__(256, 4)
void ln_kernel(const float* __restrict__ x, const float* __restrict__ res,
               const float* __restrict__ g, const float* __restrict__ bvec,
               float* __restrict__ outf, unsigned short* __restrict__ outb) {
    const int Dm = 768;
    int row = blockIdx.x;
    int tid = threadIdx.x;
    f32x4 v = {0.f, 0.f, 0.f, 0.f};
    float sum = 0.f, sq = 0.f;
    if (tid < 192) {
        f32x4 xv = ((const f32x4*)(x + (size_t)row * Dm))[tid];
        f32x4 rv = ((const f32x4*)(res + (size_t)row * Dm))[tid];
        v = xv + rv;
        sum = v.x + v.y + v.z + v.w;
        sq = v.x * v.x + v.y * v.y + v.z * v.z + v.w * v.w;
    }
#pragma unroll
    for (int d = 1; d < 64; d <<= 1) {
        sum += __shfl_xor(sum, d, 64);
        sq += __shfl_xor(sq, d, 64);
    }
    __shared__ float ps[8];
    int lane = tid & 63, wid = tid >> 6;
    if (lane == 0) { ps[wid] = sum; ps[wid + 4] = sq; }
    __syncthreads();
    sum = ps[0] + ps[1] + ps[2] + ps[3];
    sq = ps[4] + ps[5] + ps[6] + ps[7];
    float mu = sum * (1.0f / 768.0f);
    float var = sq * (1.0f / 768.0f) - mu * mu;
    float rsg = rsqrtf(var + 1e-5f);
    if (tid < 192) {
        f32x4 gv = ((const f32x4*)g)[tid];
        f32x4 bv = ((const f32x4*)bvec)[tid];
        f32x4 ov;
#pragma unroll
        for (int e = 0; e < 4; e++) ov[e] = (v[e] - mu) * rsg * gv[e] + bv[e];
        ((f32x4*)(outf + (size_t)row * Dm))[tid] = ov;
        if constexpr (WRITE_B) {
            s16x4 pb;
#pragma unroll
            for (int e = 0; e < 4; e++) pb[e] = (short)f2b(ov[e]);
            ((s16x4*)(outb + (size_t)row * Dm))[tid] = pb;
        }
    }
}

// ---------------- launch ----------------
extern "C" void kernel_launch(void* const* d_in, const int* in_sizes, int n_in,
                              void* d_out, int out_size, void* d_ws, size_t ws_size,
                              hipStream_t stream) {
    (void)in_sizes; (void)n_in; (void)out_size; (void)ws_size;
    const float* x         = (const float*)d_in[0];
    const float* attn_bias = (const float*)d_in[1];
    const float* in_proj_w = (const float*)d_in[2];
    const float* in_proj_b = (const float*)d_in[3];
    const float* out_w     = (const float*)d_in[4];
    const float* out_b     = (const float*)d_in[5];
    const float* ff1_w     = (const float*)d_in[6];
    const float* ff1_b     = (const float*)d_in[7];
    const float* ff2_w     = (const float*)d_in[8];
    const float* ff2_b     = (const float*)d_in[9];
    const float* ln1_g     = (const float*)d_in[10];
    const float* ln1_b     = (const float*)d_in[11];
    const float* ln2_g     = (const float*)d_in[12];
    const float* ln2_b     = (const float*)d_in[13];

    const int NTOK = 4096;        // B*L
    char* ws = (char*)d_ws;
    size_t off = 0;
    auto alloc = [&](size_t bytes) { void* p = ws + off; off += (bytes + 255) & ~(size_t)255; return p; };
    unsigned short* xb    = (unsigned short*)alloc((size_t)NTOK * 768 * 2);
    unsigned short* wqkv  = (unsigned short*)alloc((size_t)2304 * 768 * 2);
    unsigned short* wout  = (unsigned short*)alloc((size_t)768 * 768 * 2);
    unsigned short* wff1  = (unsigned short*)alloc((size_t)2048 * 768 * 2);
    unsigned short* wff2  = (unsigned short*)alloc((size_t)768 * 2048 * 2);
    unsigned short* qkvb  = (unsigned short*)alloc((size_t)NTOK * 2304 * 2);
    unsigned short* attnb = (unsigned short*)alloc((size_t)NTOK * 768 * 2);
    float*          aproj = (float*)alloc((size_t)NTOK * 768 * 4);
    float*          x1f   = (float*)alloc((size_t)NTOK * 768 * 4);
    unsigned short* x1b   = (unsigned short*)alloc((size_t)NTOK * 768 * 2);
    // aliases (lifetimes are disjoint):
    unsigned short* h1b  = qkvb;     // [4096,2048] bf16 fits in qkv region
    float*          ff2o = aproj;    // [4096,768] f32, aproj dead after LN1
    unsigned short* ebuf = (unsigned short*)aproj;  // exp(bias) bf16, 8.4MB <= 12.6MB;
                                                    // live [cvt6, attn] — aproj live [outproj, LN1]

    // fused conversions + exp(bias), one launch (3211264 f32x4 -> grid 12544)
    cvt6_kernel<<<dim3(12544), 256, 0, stream>>>(x, in_proj_w, out_w, ff1_w, ff2_w, attn_bias,
                                                 xb, wqkv, wout, wff1, wff2, ebuf);

    // qkv = x @ in_proj_w^T + b        [4096, 2304] bf16   grid 36x64 = 2304 (5/CU)
    gemm_ho<0><<<dim3(2304 / 64, NTOK / 64), 256, 0, stream>>>(xb, wqkv, in_proj_b, qkvb, NTOK, 2304, 768);
    // attention                         grid 512 (XCD-swizzled 1-D)
    attn_kernel<<<dim3(512), 256, 0, stream>>>(qkvb, ebuf, attnb);
    // attn @ out_w^T + b               [4096, 768] f32     grid 12x64 = 768 (5/CU)
    gemm_ho<1><<<dim3(768 / 64, NTOK / 64), 256, 0, stream>>>(attnb, wout, out_b, aproj, NTOK, 768, 768);
    // x1 = LN1(x + aproj)              f32 + bf16
    ln_kernel<1><<<dim3(NTOK), 256, 0, stream>>>(x, aproj, ln1_g, ln1_b, x1f, x1b);
    // h = gelu(x1 @ ff1^T + b)         [4096, 2048] bf16   grid 32x64 = 2048 (5/CU)
    gemm_ho<2><<<dim3(2048 / 64, NTOK / 64), 256, 0, stream>>>(x1b, wff1, ff1_b, h1b, NTOK, 2048, 768);
    // ff2 = h @ ff2^T + b              [4096, 768] f32     grid 12x64 = 768 (5/CU)
    gemm_ho<1><<<dim3(768 / 64, NTOK / 64), 256, 0, stream>>>(h1b, wff2, ff2_b, ff2o, NTOK, 768, 2048);
    // out = LN2(x1 + ff2)              f32 -> d_out
    ln_kernel<0><<<dim3(NTOK), 256, 0, stream>>>(x1f, ff2o, ln2_g, ln2_b, (float*)d_out, nullptr);
}